// Round 11
// baseline (711.315 us; speedup 1.0000x reference)
//
#include <hip/hip_runtime.h>
#include <hip/hip_bf16.h>
#include <math.h>

#define B_ 2
#define K_ 2
#define NN_ 4096
#define T_ 8
#define C_ 3
#define H_ 192
#define S_ 1638
#define KK_ 16
#define E_ (S_*KK_)          // 26208
#define NROW (B_*K_*S_)      // 6552
#define SHARP_ 5.0f

typedef __hip_bfloat16 bf;
typedef unsigned long long ull;
typedef __bf16 bf16x8 __attribute__((ext_vector_type(8)));
typedef float f32x4 __attribute__((ext_vector_type(4)));

__device__ int   g_isbf16;
__device__ int   g_viol;
__device__ __align__(16) float g_var[B_*NN_];
__device__ __align__(16) float g_accum[B_*2];
__device__ __align__(16) int   g_topidx[B_*S_];
__device__ __align__(16) float g_possel[B_*S_*3];
__device__ __align__(16) float g_masksel[B_*S_];
__device__ __align__(16) float g_x0[NROW*10];
__device__ __align__(16) int   g_knn[B_*E_];
__device__ __align__(16) float g_ea[B_*E_*4];
__device__ __align__(16) int   g_indeg[B_*S_];
__device__ __align__(16) int   g_cursor[B_*S_];
__device__ __align__(16) int   g_off[B_*(S_+1)];
__device__ __align__(16) int   g_list[B_*E_];
__device__ __align__(16) float g_P[(size_t)NROW*H_];       // P (fp32, read once/node)
__device__ __align__(16) bf    g_Qbf[(size_t)NROW*H_];     // Q (bf16, gathered deg x)
__device__ __align__(16) float g_h[(size_t)NROW*H_];
__device__ __align__(16) bf    g_hbf[(size_t)NROW*H_];
__device__ __align__(16) bf    g_abf[(size_t)NROW*H_];     // aggregated gelu sums
__device__ __align__(16) bf    g_hh[(size_t)NROW*H_];
__device__ __align__(16) bf    g_t[(size_t)NROW*H_];
__device__ __align__(16) bf    g_w2p[(size_t)11*H_*H_];
__device__ __align__(16) bf    g_wcp[(size_t)9*H_*384];

__device__ __forceinline__ float bf2f(bf x){ return __bfloat162float(x); }
__device__ __forceinline__ float LD(const void* p, long i){
  return g_isbf16 ? __bfloat162float(((const bf*)p)[i]) : ((const float*)p)[i];
}
__device__ __forceinline__ float gelu_f(float x){ return 0.5f*x*(1.0f + erff(x*0.70710678118654752f)); }
__device__ __forceinline__ ull shfl_xor_u64(ull v, int m){
  unsigned lo = (unsigned)v, hi = (unsigned)(v >> 32);
  lo = __shfl_xor(lo, m, 64); hi = __shfl_xor(hi, m, 64);
  return ((ull)hi << 32) | lo;
}

// ---------------- zero small state + input dtype detect (block 0) ----------------
__global__ void k_vz(const void* a, const void* b, const void* c){
  int tid = blockIdx.x*256 + threadIdx.x;
  if (tid < B_*S_){ g_indeg[tid]=0; g_cursor[tid]=0; }
  if (tid < B_*2) g_accum[tid]=0.f;
  if (blockIdx.x == 0){
    int t = threadIdx.x;
    const bf* pa = (const bf*)a; const bf* pb = (const bf*)b; const bf* pc = (const bf*)c;
    int bad = 0;
    #pragma unroll
    for (int s = 0; s < 2; ++s){
      float va = __bfloat162float(pa[t + s*256]);
      float vb = __bfloat162float(pb[t + s*256]);
      float vc = __bfloat162float(pc[t + s*256]);
      if (!(fabsf(va) <= 1000.f)) bad = 1;
      if (!(fabsf(vb) <= 1000.f)) bad = 1;
      if (!(fabsf(vc) <= 1000.f)) bad = 1;
    }
    if (threadIdx.x == 0) g_viol = 0;
    __syncthreads();
    if (bad) atomicOr(&g_viol, 1);
    __syncthreads();
    if (threadIdx.x == 0) g_isbf16 = (g_viol == 0) ? 1 : 0;
  }
}

// ---------------- var_pp, np pairwise-8 semantics ----------------
__global__ void k_var(const void* __restrict__ vel){
  int b = blockIdx.y;
  int n = blockIdx.x*256 + threadIdx.x;
  float v = 0.f;
  #pragma unroll
  for (int c = 0; c < 3; ++c){
    float x[8];
    #pragma unroll
    for (int t = 0; t < 8; ++t)
      x[t] = LD(vel, ((long)(b*T_+t)*NN_ + n)*3 + c);
    float m = __fadd_rn(__fadd_rn(__fadd_rn(x[0],x[1]), __fadd_rn(x[2],x[3])),
                        __fadd_rn(__fadd_rn(x[4],x[5]), __fadd_rn(x[6],x[7]))) / 8.0f;
    float d[8];
    #pragma unroll
    for (int t = 0; t < 8; ++t){ float dd = __fadd_rn(x[t], -m); d[t] = __fmul_rn(dd,dd); }
    float sv = __fadd_rn(__fadd_rn(__fadd_rn(d[0],d[1]), __fadd_rn(d[2],d[3])),
                         __fadd_rn(__fadd_rn(d[4],d[5]), __fadd_rn(d[6],d[7])));
    v = __fadd_rn(v, sv / 7.0f);
  }
  g_var[b*NN_ + n] = v;
  float s1 = v, s2 = v*v;
  #pragma unroll
  for (int o = 32; o; o >>= 1){ s1 += __shfl_xor(s1,o,64); s2 += __shfl_xor(s2,o,64); }
  __shared__ float r1[4], r2[4];
  int lane = threadIdx.x & 63, wid = threadIdx.x >> 6;
  if (!lane){ r1[wid]=s1; r2[wid]=s2; }
  __syncthreads();
  if (threadIdx.x == 0){
    atomicAdd(&g_accum[b*2+0], r1[0]+r1[1]+r1[2]+r1[3]);
    atomicAdd(&g_accum[b*2+1], r2[0]+r2[1]+r2[2]+r2[3]);
  }
}

// ---------------- stable rank-based top-S: one wave per node ----------------
__global__ __launch_bounds__(256) void k_rank(){
  int b = blockIdx.y;
  int i = blockIdx.x*4 + (threadIdx.x >> 6);
  int lane = threadIdx.x & 63;
  float vi = g_var[b*NN_+i];
  int rank = 0;
  for (int j = lane; j < NN_; j += 64){
    float vj = g_var[b*NN_+j];
    rank += ((vj > vi) || (vj == vi && j < i)) ? 1 : 0;
  }
  #pragma unroll
  for (int o = 32; o; o >>= 1) rank += __shfl_xor(rank, o, 64);
  if (lane == 0 && rank < S_) g_topidx[b*S_ + rank] = i;
}

// ---------------- gather + soft-mask (fused sigmoid) ----------------
__global__ void k_gather(const void* __restrict__ pos, const void* __restrict__ ub,
                         const void* __restrict__ vel, const void* __restrict__ air){
  int gi = blockIdx.x*256 + threadIdx.x;
  if (gi >= B_*S_) return;
  int b = gi / S_, s = gi - b*S_;
  int node = g_topidx[gi];
  float px = LD(pos, ((long)b*NN_+node)*3+0);
  float py = LD(pos, ((long)b*NN_+node)*3+1);
  float pz = LD(pos, ((long)b*NN_+node)*3+2);
  g_possel[gi*3+0]=px; g_possel[gi*3+1]=py; g_possel[gi*3+2]=pz;
  float S1 = g_accum[b*2], S2 = g_accum[b*2+1];
  float mean = S1*(1.f/NN_);
  float sd = sqrtf(fmaxf((S2 - S1*S1*(1.f/NN_))*(1.f/(NN_-1)), 0.f));
  float vf = g_var[b*NN_+node];
  float z = (vf-mean)/(sd+1e-8f);
  float sig = 1.f/(1.f+expf(-SHARP_*z));
  g_masksel[gi] = sig*(1.f - LD(air, b*NN_+node));
  float vl0 = LD(vel, ((long)(b*T_+7)*NN_+node)*3+0);
  float vl1 = LD(vel, ((long)(b*T_+7)*NN_+node)*3+1);
  float vl2 = LD(vel, ((long)(b*T_+7)*NN_+node)*3+2);
  for (int k = 0; k < K_; ++k){
    long row = (long)(b*K_+k)*S_ + s;
    float* x = g_x0 + row*10;
    x[0]=LD(ub, ((long)(b*K_+k)*NN_+node)*3+0);
    x[1]=LD(ub, ((long)(b*K_+k)*NN_+node)*3+1);
    x[2]=LD(ub, ((long)(b*K_+k)*NN_+node)*3+2);
    x[3]=vl0; x[4]=vl1; x[5]=vl2;
    x[6]=px;  x[7]=py;  x[8]=pz;
    x[9]=vf;
  }
}

// ---------------- KNN: one wave per query node ----------------
__global__ __launch_bounds__(256) void k_knn(){
  __shared__ float px[S_], py[S_], pz[S_];
  int b = blockIdx.y;
  int j = blockIdx.x*4 + (threadIdx.x >> 6);
  int lane = threadIdx.x & 63;
  for (int t = threadIdx.x; t < S_; t += 256){
    px[t] = g_possel[(b*S_+t)*3+0];
    py[t] = g_possel[(b*S_+t)*3+1];
    pz[t] = g_possel[(b*S_+t)*3+2];
  }
  __syncthreads();
  if (j >= S_) return;
  float xj=px[j], yj=py[j], zj=pz[j];
  float dist[KK_]; int id[KK_];
  #pragma unroll
  for (int t = 0; t < KK_; ++t){ dist[t]=3.0e38f; id[t]=0x7fffffff; }
  for (int c = lane; c < S_; c += 64){
    if (c == j) continue;
    float dx=__fadd_rn(px[c],-xj), dy=__fadd_rn(py[c],-yj), dz=__fadd_rn(pz[c],-zj);
    float d2 = __fadd_rn(__fadd_rn(__fmul_rn(dx,dx), __fmul_rn(dy,dy)), __fmul_rn(dz,dz));
    if (d2 < dist[KK_-1]){
      int p = 0;
      #pragma unroll
      for (int q = 0; q < KK_; ++q) p += (dist[q] <= d2) ? 1 : 0;
      #pragma unroll
      for (int q = KK_-1; q >= 1; --q){
        bool mv = (q > p);
        dist[q] = mv ? dist[q-1] : dist[q];
        id[q]   = mv ? id[q-1]   : id[q];
      }
      #pragma unroll
      for (int q = 0; q < KK_; ++q){ if (q == p){ dist[q] = d2; id[q] = c; } }
    }
  }
  ull mykey = 0;
  #pragma unroll
  for (int t = 0; t < KK_; ++t){
    ull k = (((ull)__float_as_uint(dist[0])) << 32) | (unsigned)id[0];
    ull m = k;
    #pragma unroll
    for (int o = 32; o; o >>= 1){ ull other = shfl_xor_u64(m, o); m = (other < m) ? other : m; }
    if (k == m){
      #pragma unroll
      for (int q = 0; q < KK_-1; ++q){ dist[q]=dist[q+1]; id[q]=id[q+1]; }
      dist[KK_-1] = 3.0e38f; id[KK_-1] = 0x7fffffff;
    }
    if (lane == t) mykey = m;
  }
  if (lane < KK_){
    int i = (int)(mykey & 0xffffffffu);
    g_knn[(b*S_+j)*KK_ + lane] = i;
    float rx = __fadd_rn(px[i],-xj), ry = __fadd_rn(py[i],-yj), rz = __fadd_rn(pz[i],-zj);
    float dd = sqrtf(__fadd_rn(__fadd_rn(__fmul_rn(rx,rx), __fmul_rn(ry,ry)), __fmul_rn(rz,rz)));
    float* o = g_ea + ((long)b*E_ + j*KK_ + lane)*4;
    o[0]=rx; o[1]=ry; o[2]=rz; o[3]=dd;
    atomicAdd(&g_indeg[b*S_+i], 1);
  }
}

__global__ void k_scan(){
  __shared__ int sA[2048], sB[2048];
  int b = blockIdx.x, tid = threadIdx.x;   // 1024
  for (int i = tid; i < 2048; i += 1024) sA[i] = (i < S_) ? g_indeg[b*S_+i] : 0;
  __syncthreads();
  int *src = sA, *dst = sB;
  for (int d = 1; d < 2048; d <<= 1){
    for (int i = tid; i < 2048; i += 1024) dst[i] = src[i] + (i >= d ? src[i-d] : 0);
    __syncthreads();
    int* t2 = src; src = dst; dst = t2;
  }
  if (tid == 0) g_off[b*(S_+1)] = 0;
  for (int i = tid; i < S_; i += 1024) g_off[b*(S_+1)+i+1] = src[i];
}

__global__ void k_fill(){
  int idx = blockIdx.x*256 + threadIdx.x;
  if (idx >= B_*E_) return;
  int b = idx / E_, e = idx - b*E_;
  int i = g_knn[idx];
  int slot = atomicAdd(&g_cursor[b*S_+i], 1);
  g_list[b*E_ + g_off[b*(S_+1)+i] + slot] = e;
}

// ------- fat prep kernel: pack_w2 (blocks 0..1583) + pack_wc (1584..4175) + initout (4176..4367) -------
__global__ void k_prep(const void* __restrict__ c0w2, const void* __restrict__ cw2,
                       const void* __restrict__ hw1, const void* __restrict__ cw1,
                       const void* __restrict__ ub, const void* __restrict__ air,
                       float* __restrict__ out){
  int bx = blockIdx.x;
  if (bx < 1584){
    int gi = bx*256 + threadIdx.x;
    if (gi >= 11*H_*H_) return;
    int mat = gi / (H_*H_), r = gi - mat*(H_*H_);
    int k = r / H_, n = r - (r/H_)*H_;
    float v;
    if (mat == 0)      v = LD(c0w2, (long)k*H_ + n);
    else if (mat <= 9) v = LD(cw2, (long)(mat-1)*H_*H_ + (long)k*H_ + n);
    else               v = LD(hw1, (long)k*H_ + n);
    int t = k>>5, q = (k>>3)&3, jj = k&7;
    g_w2p[(size_t)mat*H_*H_ + (((t*4+q)*H_ + n)*8 + jj)] = __float2bfloat16(v);
  } else if (bx < 4176){
    int gi = (bx-1584)*256 + threadIdx.x;
    if (gi >= 9*H_*384) return;
    int l = gi / (H_*384), r = gi - l*(H_*384);
    int k = r / 384, n = r - (r/384)*384;
    long base = (long)l*388*H_;
    float v;
    if (n < H_) v = LD(cw1, base + (long)k*H_ + n) - LD(cw1, base + (long)(H_+k)*H_ + n);
    else        v = LD(cw1, base + (long)(H_+k)*H_ + (n-H_));
    int t = k>>5, q = (k>>3)&3, jj = k&7;
    g_wcp[(size_t)l*(H_*384) + (((t*4+q)*384 + n)*8 + jj)] = __float2bfloat16(v);
  } else {
    int gi = (bx-4176)*256 + threadIdx.x;   // 49152 outputs
    int n = (gi/3) % NN_;
    int b = gi / (K_*NN_*C_);
    float a = 1.f - LD(air, b*NN_+n);
    out[gi] = LD(ub, gi) * a;
  }
}

// ---------------- conv0 node projection (K=10), weights in LDS ----------------
__global__ __launch_bounds__(256) void k_proj0(const void* __restrict__ w1){
  __shared__ float xs[16][10];
  __shared__ float wP[10][192];
  __shared__ float wQ[10][192];
  int tid = threadIdx.x;
  long rowBase = (long)blockIdx.x * 16;
  for (int idx = tid; idx < 1920; idx += 256){
    int f = idx / 192, n = idx - (idx/192)*192;
    float a = LD(w1, f*H_+n), b = LD(w1, (10+f)*H_+n);
    wP[f][n] = a - b; wQ[f][n] = b;
  }
  for (int idx = tid; idx < 160; idx += 256){
    int r = idx / 10, f = idx - (idx/10)*10;
    long row = rowBase + r; if (row >= NROW) row = NROW-1;
    xs[r][f] = g_x0[row*10 + f];
  }
  __syncthreads();
  for (int o = tid; o < 16*384; o += 256){
    int r = o / 384, n = o - (o/384)*384;
    long row = rowBase + r;
    if (row >= NROW) continue;
    float acc = 0.f;
    if (n < 192){
      #pragma unroll
      for (int f = 0; f < 10; ++f) acc += xs[r][f]*wP[f][n];
      g_P[row*192 + n] = acc;
    } else {
      int nc = n - 192;
      #pragma unroll
      for (int f = 0; f < 10; ++f) acc += xs[r][f]*wQ[f][nc];
      g_Qbf[row*192 + nc] = __float2bfloat16(acc);
    }
  }
}

// ---------------- MFMA GEMM: PQ projection, N=384 ----------------
__global__ __launch_bounds__(256) void k_gemmPQ(int bOff, int M){
  const bf* A  = g_hbf;
  const bf* Bp = g_wcp + bOff;
  int wave = threadIdx.x >> 6, lane = threadIdx.x & 63;
  int q = lane >> 4, l16 = lane & 15;
  long rowBase = (long)blockIdx.x * 32;
  f32x4 acc[2][6];
  #pragma unroll
  for (int rt = 0; rt < 2; ++rt)
    #pragma unroll
    for (int ct = 0; ct < 6; ++ct) acc[rt][ct] = (f32x4){0.f,0.f,0.f,0.f};
  #pragma unroll
  for (int t = 0; t < 6; ++t){
    int kof = t*32 + q*8;
    bf16x8 af[2], bfr[6];
    #pragma unroll
    for (int rt = 0; rt < 2; ++rt){
      long r = rowBase + rt*16 + l16;
      if (r >= M) r = M-1;
      af[rt] = *reinterpret_cast<const bf16x8*>(A + r*192 + kof);
    }
    #pragma unroll
    for (int ct = 0; ct < 6; ++ct){
      int n = wave*96 + ct*16 + l16;
      bfr[ct] = *reinterpret_cast<const bf16x8*>(Bp + (((t*4+q)*384 + n)*8));
    }
    #pragma unroll
    for (int rt = 0; rt < 2; ++rt)
      #pragma unroll
      for (int ct = 0; ct < 6; ++ct)
        acc[rt][ct] = __builtin_amdgcn_mfma_f32_16x16x32_bf16(af[rt], bfr[ct], acc[rt][ct], 0,0,0);
  }
  #pragma unroll
  for (int rt = 0; rt < 2; ++rt){
    #pragma unroll
    for (int ct = 0; ct < 6; ++ct){
      int col = wave*96 + ct*16 + l16;
      #pragma unroll
      for (int r = 0; r < 4; ++r){
        long row = rowBase + rt*16 + q*4 + r;
        if (row < M){
          float v = acc[rt][ct][r];
          if (col < 192) g_P[row*192 + col] = v;
          else           g_Qbf[row*192 + (col-192)] = __float2bfloat16(v);
        }
      }
    }
  }
}

// ---------------- fused MFMA GEMM (m2) + deg*b2 + LayerNorm + residual ----------------
template<int RES>
__global__ __launch_bounds__(256) void k_gemmln(const void* __restrict__ biasB, long biasO,
                                                const void* __restrict__ gB, long gO,
                                                const void* __restrict__ beB, long beO,
                                                int bOff, int M){
  const bf* A  = g_abf;
  const bf* Bp = g_w2p + bOff;
  int wave = threadIdx.x >> 6, lane = threadIdx.x & 63;
  int q = lane >> 4, l16 = lane & 15;
  long rowBase = (long)blockIdx.x * 32;
  f32x4 acc[2][3];
  #pragma unroll
  for (int rt = 0; rt < 2; ++rt)
    #pragma unroll
    for (int ct = 0; ct < 3; ++ct) acc[rt][ct] = (f32x4){0.f,0.f,0.f,0.f};
  #pragma unroll
  for (int t = 0; t < 6; ++t){
    int kof = t*32 + q*8;
    bf16x8 af[2], bfr[3];
    #pragma unroll
    for (int rt = 0; rt < 2; ++rt){
      long r = rowBase + rt*16 + l16;
      if (r >= M) r = M-1;
      af[rt] = *reinterpret_cast<const bf16x8*>(A + r*192 + kof);
    }
    #pragma unroll
    for (int ct = 0; ct < 3; ++ct){
      int n = wave*48 + ct*16 + l16;
      bfr[ct] = *reinterpret_cast<const bf16x8*>(Bp + (((t*4+q)*192 + n)*8));
    }
    #pragma unroll
    for (int rt = 0; rt < 2; ++rt)
      #pragma unroll
      for (int ct = 0; ct < 3; ++ct)
        acc[rt][ct] = __builtin_amdgcn_mfma_f32_16x16x32_bf16(af[rt], bfr[ct], acc[rt][ct], 0,0,0);
  }
  __shared__ float tile[32][200];
  __shared__ float srow[32], rrow[32];
  #pragma unroll
  for (int rt = 0; rt < 2; ++rt){
    #pragma unroll
    for (int ct = 0; ct < 3; ++ct){
      int col = wave*48 + ct*16 + l16;
      float bb = LD(biasB, biasO + col);
      #pragma unroll
      for (int r = 0; r < 4; ++r){
        int lr = rt*16 + q*4 + r;
        long row = rowBase + lr;
        long rowc = (row < M) ? row : (M-1);
        int bk = (int)(rowc / S_); int i = (int)(rowc - (long)bk*S_); int b = bk >> 1;
        float degf = (float)(g_off[b*(S_+1)+i+1] - g_off[b*(S_+1)+i]);
        tile[lr][col] = acc[rt][ct][r] + degf*bb;
      }
    }
  }
  __syncthreads();
  {
    int lr = threadIdx.x >> 3;
    int k8 = threadIdx.x & 7;
    float s = 0.f, qq = 0.f;
    for (int c = k8; c < 192; c += 8){ float x = tile[lr][c]; s += x; qq += x*x; }
    #pragma unroll
    for (int o = 1; o < 8; o <<= 1){ s += __shfl_xor(s,o,64); qq += __shfl_xor(qq,o,64); }
    if (k8 == 0){
      float mu = s*(1.f/H_);
      float var = qq*(1.f/H_) - mu*mu;
      srow[lr] = mu;
      rrow[lr] = rsqrtf(fmaxf(var, 0.f) + 1e-5f);
    }
  }
  __syncthreads();
  for (int o = threadIdx.x; o < 32*192; o += 256){
    int lr = o / 192, col = o - (o/192)*192;
    long row = rowBase + lr;
    if (row < M){
      float y = (tile[lr][col] - srow[lr])*rrow[lr]*LD(gB,gO+col) + LD(beB,beO+col);
      if (RES) y += g_h[row*192 + col];
      g_h[row*192 + col] = y;
      g_hbf[row*192 + col] = __float2bfloat16(y);
    }
  }
}

// ---------------- head: LN + GEMM + gelu -> g_t ----------------
__global__ __launch_bounds__(256) void k_gemmhead(const void* __restrict__ gB,
                                                  const void* __restrict__ beB,
                                                  const void* __restrict__ biasB,
                                                  int bOff, int M){
  const bf* Bp = g_w2p + bOff;
  int wave = threadIdx.x >> 6, lane = threadIdx.x & 63;
  int q = lane >> 4, l16 = lane & 15;
  long rowBase = (long)blockIdx.x * 32;
  __shared__ float tile[32][200];
  __shared__ bf hb_s[32][216];
  __shared__ float srow[32], rrow[32];
  for (int o = threadIdx.x; o < 32*192; o += 256){
    int lr = o / 192, col = o - (o/192)*192;
    long row = rowBase + lr;
    long rowc = (row < M) ? row : (M-1);
    tile[lr][col] = g_h[rowc*192 + col];
  }
  __syncthreads();
  {
    int lr = threadIdx.x >> 3;
    int k8 = threadIdx.x & 7;
    float s = 0.f, qq = 0.f;
    for (int c = k8; c < 192; c += 8){ float x = tile[lr][c]; s += x; qq += x*x; }
    #pragma unroll
    for (int o = 1; o < 8; o <<= 1){ s += __shfl_xor(s,o,64); qq += __shfl_xor(qq,o,64); }
    if (k8 == 0){
      float mu = s*(1.f/H_);
      float var = qq*(1.f/H_) - mu*mu;
      srow[lr] = mu;
      rrow[lr] = rsqrtf(fmaxf(var, 0.f) + 1e-5f);
    }
  }
  __syncthreads();
  for (int o = threadIdx.x; o < 32*192; o += 256){
    int lr = o / 192, col = o - (o/192)*192;
    hb_s[lr][col] = __float2bfloat16((tile[lr][col] - srow[lr])*rrow[lr]*LD(gB,col) + LD(beB,col));
  }
  __syncthreads();
  f32x4 acc[2][3];
  #pragma unroll
  for (int rt = 0; rt < 2; ++rt)
    #pragma unroll
    for (int ct = 0; ct < 3; ++ct) acc[rt][ct] = (f32x4){0.f,0.f,0.f,0.f};
  #pragma unroll
  for (int t = 0; t < 6; ++t){
    int kof = t*32 + q*8;
    bf16x8 af[2], bfr[3];
    #pragma unroll
    for (int rt = 0; rt < 2; ++rt)
      af[rt] = *reinterpret_cast<const bf16x8*>(&hb_s[rt*16 + l16][kof]);
    #pragma unroll
    for (int ct = 0; ct < 3; ++ct){
      int n = wave*48 + ct*16 + l16;
      bfr[ct] = *reinterpret_cast<const bf16x8*>(Bp + (((t*4+q)*192 + n)*8));
    }
    #pragma unroll
    for (int rt = 0; rt < 2; ++rt)
      #pragma unroll
      for (int ct = 0; ct < 3; ++ct)
        acc[rt][ct] = __builtin_amdgcn_mfma_f32_16x16x32_bf16(af[rt], bfr[ct], acc[rt][ct], 0,0,0);
  }
  #pragma unroll
  for (int rt = 0; rt < 2; ++rt){
    #pragma unroll
    for (int ct = 0; ct < 3; ++ct){
      int col = wave*48 + ct*16 + l16;
      float bb = LD(biasB, col);
      #pragma unroll
      for (int r = 0; r < 4; ++r){
        long row = rowBase + rt*16 + q*4 + r;
        if (row < M) g_t[row*192 + col] = __float2bfloat16(gelu_f(acc[rt][ct][r] + bb));
      }
    }
  }
}

// ---------------- fused edge-compute + CSR aggregate (unroll x4) ----------------
__global__ __launch_bounds__(192) void k_aggedge(const void* __restrict__ w1cB, long w1cO,
                                                 const void* __restrict__ b1B, long b1O){
  int row = blockIdx.x;   // NROW
  int col = threadIdx.x;  // 192
  int bk = row / S_, i = row - bk*S_, b = bk >> 1;
  int off = g_off[b*(S_+1)+i];
  int deg = g_off[b*(S_+1)+i+1] - off;
  float w0 = LD(w1cB, w1cO+col),       w1v = LD(w1cB, w1cO+H_+col);
  float w2v = LD(w1cB, w1cO+2*H_+col), w3v = LD(w1cB, w1cO+3*H_+col);
  float base = g_P[(size_t)row*H_ + col] + LD(b1B, b1O+col);
  const int* lst = g_list + b*E_ + off;
  const bf* Q = g_Qbf + (size_t)bk*S_*H_;
  const float* EA = g_ea + (size_t)b*E_*4;
  float acc = 0.f;
  int d = 0;
  for (; d + 4 <= deg; d += 4){
    int e0 = lst[d], e1 = lst[d+1], e2 = lst[d+2], e3 = lst[d+3];
    float4 a0 = *reinterpret_cast<const float4*>(EA + (size_t)e0*4);
    float4 a1 = *reinterpret_cast<const float4*>(EA + (size_t)e1*4);
    float4 a2 = *reinterpret_cast<const float4*>(EA + (size_t)e2*4);
    float4 a3 = *reinterpret_cast<const float4*>(EA + (size_t)e3*4);
    float q0 = bf2f(Q[(size_t)(e0>>4)*H_ + col]);
    float q1 = bf2f(Q[(size_t)(e1>>4)*H_ + col]);
    float q2 = bf2f(Q[(size_t)(e2>>4)*H_ + col]);
    float q3 = bf2f(Q[(size_t)(e3>>4)*H_ + col]);
    acc += gelu_f(base + q0 + a0.x*w0 + a0.y*w1v + a0.z*w2v + a0.w*w3v);
    acc += gelu_f(base + q1 + a1.x*w0 + a1.y*w1v + a1.z*w2v + a1.w*w3v);
    acc += gelu_f(base + q2 + a2.x*w0 + a2.y*w1v + a2.z*w2v + a2.w*w3v);
    acc += gelu_f(base + q3 + a3.x*w0 + a3.y*w1v + a3.z*w2v + a3.w*w3v);
  }
  for (; d < deg; ++d){
    int e = lst[d];
    float4 a = *reinterpret_cast<const float4*>(EA + (size_t)e*4);
    float qv = bf2f(Q[(size_t)(e>>4)*H_ + col]);
    acc += gelu_f(base + qv + a.x*w0 + a.y*w1v + a.z*w2v + a.w*w3v);
  }
  g_abf[(size_t)row*H_ + col] = __float2bfloat16(acc);
}

// ---------------- final output rows ----------------
__global__ void k_headout(const void* __restrict__ w2, const void* __restrict__ b2,
                          const void* __restrict__ ub, const void* __restrict__ air,
                          float* __restrict__ out){
  int row = blockIdx.x*4 + (threadIdx.x >> 6);
  int lane = threadIdx.x & 63;
  if (row >= NROW) return;
  float t0 = bf2f(g_t[(size_t)row*H_ + lane]);
  float t1 = bf2f(g_t[(size_t)row*H_ + lane + 64]);
  float t2 = bf2f(g_t[(size_t)row*H_ + lane + 128]);
  float d[3];
  #pragma unroll
  for (int c = 0; c < 3; ++c){
    float p = t0*LD(w2,lane*3+c) + t1*LD(w2,(lane+64)*3+c) + t2*LD(w2,(lane+128)*3+c);
    #pragma unroll
    for (int o = 32; o; o >>= 1) p += __shfl_xor(p,o,64);
    d[c] = p + LD(b2,c);
  }
  if (lane == 0){
    int bk = row / S_, s = row - bk*S_, b = bk >> 1;
    float msk = g_masksel[b*S_+s];
    int node = g_topidx[b*S_+s];
    float am = 1.f - LD(air, b*NN_+node);
    #pragma unroll
    for (int c = 0; c < 3; ++c){
      long oi = ((long)bk*NN_ + node)*3 + c;
      out[oi] = (LD(ub,oi) + d[c]*msk)*am;
    }
  }
}

extern "C" void kernel_launch(void* const* d_in, const int* in_sizes, int n_in,
                              void* d_out, int out_size, void* d_ws, size_t ws_size,
                              hipStream_t stream) {
  (void)in_sizes; (void)n_in; (void)d_ws; (void)ws_size; (void)out_size;
  const void* u_base = d_in[0];
  const void* pos    = d_in[1];
  const void* vel    = d_in[2];
  const void* air    = d_in[3];
  const void* c0w1   = d_in[4];
  const void* c0b1   = d_in[5];
  const void* c0w2   = d_in[6];
  const void* c0b2   = d_in[7];
  const void* c0g    = d_in[8];
  const void* c0be   = d_in[9];
  const void* cw1    = d_in[10];
  const void* cb1    = d_in[11];
  const void* cw2    = d_in[12];
  const void* cb2    = d_in[13];
  const void* cg     = d_in[14];
  const void* cbe    = d_in[15];
  const void* hg     = d_in[16];
  const void* hbe    = d_in[17];
  const void* hw1    = d_in[18];
  const void* hb1    = d_in[19];
  const void* hw2    = d_in[20];
  const void* hb2    = d_in[21];
  float* out = (float*)d_out;

  k_vz<<<13, 256, 0, stream>>>(u_base, pos, vel);
  k_var<<<dim3(16, B_), 256, 0, stream>>>(vel);
  k_rank<<<dim3(NN_/4, B_), 256, 0, stream>>>();
  k_gather<<<13, 256, 0, stream>>>(pos, u_base, vel, air);
  k_knn<<<dim3((S_+3)/4, B_), 256, 0, stream>>>();
  k_scan<<<B_, 1024, 0, stream>>>();
  k_fill<<<205, 256, 0, stream>>>();
  k_prep<<<4368, 256, 0, stream>>>(c0w2, cw2, hw1, cw1, u_base, air, out);
  k_proj0<<<410, 256, 0, stream>>>(c0w1);

  const int GN = (NROW + 31) / 32;   // 205
  for (int l = 0; l < 10; ++l){
    if (l > 0) k_gemmPQ<<<GN, 256, 0, stream>>>((l-1)*H_*384, NROW);

    long w1cO = (l == 0) ? 20L*H_ : ((long)(l-1)*388 + 384)*H_;
    const void* w1cB = (l == 0) ? c0w1 : cw1;
    long lOff = (l == 0) ? 0 : (long)(l-1)*H_;
    const void* b1B = (l == 0) ? c0b1 : cb1;
    k_aggedge<<<NROW, 192, 0, stream>>>(w1cB, w1cO, b1B, lOff);

    const void* b2B = (l == 0) ? c0b2 : cb2;
    const void* gB  = (l == 0) ? c0g  : cg;
    const void* beB = (l == 0) ? c0be : cbe;
    if (l > 0) k_gemmln<1><<<GN, 256, 0, stream>>>(b2B, lOff, gB, lOff, beB, lOff, l*H_*H_, NROW);
    else       k_gemmln<0><<<GN, 256, 0, stream>>>(b2B, lOff, gB, lOff, beB, lOff, l*H_*H_, NROW);
  }

  k_gemmhead<<<GN, 256, 0, stream>>>(hg, hbe, hb1, 10*H_*H_, NROW);
  k_headout<<<NROW/4, 256, 0, stream>>>(hw2, hb2, u_base, air, out);
}

// Round 12
// 658.262 us; speedup vs baseline: 1.0806x; 1.0806x over previous
//
#include <hip/hip_runtime.h>
#include <hip/hip_bf16.h>
#include <math.h>

#define B_ 2
#define K_ 2
#define NN_ 4096
#define T_ 8
#define C_ 3
#define H_ 192
#define S_ 1638
#define KK_ 16
#define E_ (S_*KK_)          // 26208
#define NROW (B_*K_*S_)      // 6552
#define SHARP_ 5.0f

typedef __hip_bfloat16 bf;
typedef unsigned long long ull;
typedef __bf16 bf16x8 __attribute__((ext_vector_type(8)));
typedef float f32x4 __attribute__((ext_vector_type(4)));

__device__ int   g_isbf16;
__device__ int   g_viol;
__device__ __align__(16) float g_var[B_*NN_];
__device__ __align__(16) float g_accum[B_*2];
__device__ __align__(16) int   g_topidx[B_*S_];
__device__ __align__(16) float g_possel[B_*S_*3];
__device__ __align__(16) float g_masksel[B_*S_];
__device__ __align__(16) float g_x0[NROW*10];
__device__ __align__(16) int   g_knn[B_*E_];
__device__ __align__(16) float g_ea[B_*E_*4];
__device__ __align__(16) int   g_indeg[B_*S_];
__device__ __align__(16) int   g_cursor[B_*S_];
__device__ __align__(16) int   g_off[B_*(S_+1)];
__device__ __align__(16) int   g_list[B_*E_];
__device__ __align__(16) float g_P[(size_t)NROW*H_];
__device__ __align__(16) bf    g_Qbf[(size_t)NROW*H_];
__device__ __align__(16) float g_h[(size_t)NROW*H_];
__device__ __align__(16) bf    g_hbf[(size_t)NROW*H_];
__device__ __align__(16) bf    g_abf[(size_t)NROW*H_];
__device__ __align__(16) bf    g_hh[(size_t)NROW*H_];
__device__ __align__(16) bf    g_t[(size_t)NROW*H_];
__device__ __align__(16) bf    g_w2p[(size_t)11*H_*H_];
__device__ __align__(16) bf    g_wcp[(size_t)9*H_*384];

__device__ __forceinline__ float bf2f(bf x){ return __bfloat162float(x); }
__device__ __forceinline__ float LD(const void* p, long i){
  return g_isbf16 ? __bfloat162float(((const bf*)p)[i]) : ((const float*)p)[i];
}
__device__ __forceinline__ float gelu_f(float x){ return 0.5f*x*(1.0f + erff(x*0.70710678118654752f)); }
__device__ __forceinline__ ull shfl_xor_u64(ull v, int m){
  unsigned lo = (unsigned)v, hi = (unsigned)(v >> 32);
  lo = __shfl_xor(lo, m, 64); hi = __shfl_xor(hi, m, 64);
  return ((ull)hi << 32) | lo;
}

// ---------------- zero small state + input dtype detect (block 0) ----------------
__global__ void k_vz(const void* a, const void* b, const void* c){
  int tid = blockIdx.x*256 + threadIdx.x;
  if (tid < B_*S_){ g_indeg[tid]=0; g_cursor[tid]=0; }
  if (tid < B_*2) g_accum[tid]=0.f;
  if (blockIdx.x == 0){
    int t = threadIdx.x;
    const bf* pa = (const bf*)a; const bf* pb = (const bf*)b; const bf* pc = (const bf*)c;
    int bad = 0;
    #pragma unroll
    for (int s = 0; s < 2; ++s){
      float va = __bfloat162float(pa[t + s*256]);
      float vb = __bfloat162float(pb[t + s*256]);
      float vc = __bfloat162float(pc[t + s*256]);
      if (!(fabsf(va) <= 1000.f)) bad = 1;
      if (!(fabsf(vb) <= 1000.f)) bad = 1;
      if (!(fabsf(vc) <= 1000.f)) bad = 1;
    }
    if (threadIdx.x == 0) g_viol = 0;
    __syncthreads();
    if (bad) atomicOr(&g_viol, 1);
    __syncthreads();
    if (threadIdx.x == 0) g_isbf16 = (g_viol == 0) ? 1 : 0;
  }
}

// ---------------- var_pp, np pairwise-8 semantics ----------------
__global__ void k_var(const void* __restrict__ vel){
  int b = blockIdx.y;
  int n = blockIdx.x*256 + threadIdx.x;
  float v = 0.f;
  #pragma unroll
  for (int c = 0; c < 3; ++c){
    float x[8];
    #pragma unroll
    for (int t = 0; t < 8; ++t)
      x[t] = LD(vel, ((long)(b*T_+t)*NN_ + n)*3 + c);
    float m = __fadd_rn(__fadd_rn(__fadd_rn(x[0],x[1]), __fadd_rn(x[2],x[3])),
                        __fadd_rn(__fadd_rn(x[4],x[5]), __fadd_rn(x[6],x[7]))) / 8.0f;
    float d[8];
    #pragma unroll
    for (int t = 0; t < 8; ++t){ float dd = __fadd_rn(x[t], -m); d[t] = __fmul_rn(dd,dd); }
    float sv = __fadd_rn(__fadd_rn(__fadd_rn(d[0],d[1]), __fadd_rn(d[2],d[3])),
                         __fadd_rn(__fadd_rn(d[4],d[5]), __fadd_rn(d[6],d[7])));
    v = __fadd_rn(v, sv / 7.0f);
  }
  g_var[b*NN_ + n] = v;
  float s1 = v, s2 = v*v;
  #pragma unroll
  for (int o = 32; o; o >>= 1){ s1 += __shfl_xor(s1,o,64); s2 += __shfl_xor(s2,o,64); }
  __shared__ float r1[4], r2[4];
  int lane = threadIdx.x & 63, wid = threadIdx.x >> 6;
  if (!lane){ r1[wid]=s1; r2[wid]=s2; }
  __syncthreads();
  if (threadIdx.x == 0){
    atomicAdd(&g_accum[b*2+0], r1[0]+r1[1]+r1[2]+r1[3]);
    atomicAdd(&g_accum[b*2+1], r2[0]+r2[1]+r2[2]+r2[3]);
  }
}

// ---------------- stable rank-based top-S: one wave per node ----------------
__global__ __launch_bounds__(256) void k_rank(){
  int b = blockIdx.y;
  int i = blockIdx.x*4 + (threadIdx.x >> 6);
  int lane = threadIdx.x & 63;
  float vi = g_var[b*NN_+i];
  int rank = 0;
  for (int j = lane; j < NN_; j += 64){
    float vj = g_var[b*NN_+j];
    rank += ((vj > vi) || (vj == vi && j < i)) ? 1 : 0;
  }
  #pragma unroll
  for (int o = 32; o; o >>= 1) rank += __shfl_xor(rank, o, 64);
  if (lane == 0 && rank < S_) g_topidx[b*S_ + rank] = i;
}

// ---------------- gather + soft-mask (fused sigmoid) ----------------
__global__ void k_gather(const void* __restrict__ pos, const void* __restrict__ ub,
                         const void* __restrict__ vel, const void* __restrict__ air){
  int gi = blockIdx.x*256 + threadIdx.x;
  if (gi >= B_*S_) return;
  int b = gi / S_, s = gi - b*S_;
  int node = g_topidx[gi];
  float px = LD(pos, ((long)b*NN_+node)*3+0);
  float py = LD(pos, ((long)b*NN_+node)*3+1);
  float pz = LD(pos, ((long)b*NN_+node)*3+2);
  g_possel[gi*3+0]=px; g_possel[gi*3+1]=py; g_possel[gi*3+2]=pz;
  float S1 = g_accum[b*2], S2 = g_accum[b*2+1];
  float mean = S1*(1.f/NN_);
  float sd = sqrtf(fmaxf((S2 - S1*S1*(1.f/NN_))*(1.f/(NN_-1)), 0.f));
  float vf = g_var[b*NN_+node];
  float z = (vf-mean)/(sd+1e-8f);
  float sig = 1.f/(1.f+expf(-SHARP_*z));
  g_masksel[gi] = sig*(1.f - LD(air, b*NN_+node));
  float vl0 = LD(vel, ((long)(b*T_+7)*NN_+node)*3+0);
  float vl1 = LD(vel, ((long)(b*T_+7)*NN_+node)*3+1);
  float vl2 = LD(vel, ((long)(b*T_+7)*NN_+node)*3+2);
  for (int k = 0; k < K_; ++k){
    long row = (long)(b*K_+k)*S_ + s;
    float* x = g_x0 + row*10;
    x[0]=LD(ub, ((long)(b*K_+k)*NN_+node)*3+0);
    x[1]=LD(ub, ((long)(b*K_+k)*NN_+node)*3+1);
    x[2]=LD(ub, ((long)(b*K_+k)*NN_+node)*3+2);
    x[3]=vl0; x[4]=vl1; x[5]=vl2;
    x[6]=px;  x[7]=py;  x[8]=pz;
    x[9]=vf;
  }
}

// ---------------- KNN: one wave per query node ----------------
__global__ __launch_bounds__(256) void k_knn(){
  __shared__ float px[S_], py[S_], pz[S_];
  int b = blockIdx.y;
  int j = blockIdx.x*4 + (threadIdx.x >> 6);
  int lane = threadIdx.x & 63;
  for (int t = threadIdx.x; t < S_; t += 256){
    px[t] = g_possel[(b*S_+t)*3+0];
    py[t] = g_possel[(b*S_+t)*3+1];
    pz[t] = g_possel[(b*S_+t)*3+2];
  }
  __syncthreads();
  if (j >= S_) return;
  float xj=px[j], yj=py[j], zj=pz[j];
  float dist[KK_]; int id[KK_];
  #pragma unroll
  for (int t = 0; t < KK_; ++t){ dist[t]=3.0e38f; id[t]=0x7fffffff; }
  for (int c = lane; c < S_; c += 64){
    if (c == j) continue;
    float dx=__fadd_rn(px[c],-xj), dy=__fadd_rn(py[c],-yj), dz=__fadd_rn(pz[c],-zj);
    float d2 = __fadd_rn(__fadd_rn(__fmul_rn(dx,dx), __fmul_rn(dy,dy)), __fmul_rn(dz,dz));
    if (d2 < dist[KK_-1]){
      int p = 0;
      #pragma unroll
      for (int q = 0; q < KK_; ++q) p += (dist[q] <= d2) ? 1 : 0;
      #pragma unroll
      for (int q = KK_-1; q >= 1; --q){
        bool mv = (q > p);
        dist[q] = mv ? dist[q-1] : dist[q];
        id[q]   = mv ? id[q-1]   : id[q];
      }
      #pragma unroll
      for (int q = 0; q < KK_; ++q){ if (q == p){ dist[q] = d2; id[q] = c; } }
    }
  }
  ull mykey = 0;
  #pragma unroll
  for (int t = 0; t < KK_; ++t){
    ull k = (((ull)__float_as_uint(dist[0])) << 32) | (unsigned)id[0];
    ull m = k;
    #pragma unroll
    for (int o = 32; o; o >>= 1){ ull other = shfl_xor_u64(m, o); m = (other < m) ? other : m; }
    if (k == m){
      #pragma unroll
      for (int q = 0; q < KK_-1; ++q){ dist[q]=dist[q+1]; id[q]=id[q+1]; }
      dist[KK_-1] = 3.0e38f; id[KK_-1] = 0x7fffffff;
    }
    if (lane == t) mykey = m;
  }
  if (lane < KK_){
    int i = (int)(mykey & 0xffffffffu);
    g_knn[(b*S_+j)*KK_ + lane] = i;
    float rx = __fadd_rn(px[i],-xj), ry = __fadd_rn(py[i],-yj), rz = __fadd_rn(pz[i],-zj);
    float dd = sqrtf(__fadd_rn(__fadd_rn(__fmul_rn(rx,rx), __fmul_rn(ry,ry)), __fmul_rn(rz,rz)));
    float* o = g_ea + ((long)b*E_ + j*KK_ + lane)*4;
    o[0]=rx; o[1]=ry; o[2]=rz; o[3]=dd;
    atomicAdd(&g_indeg[b*S_+i], 1);
  }
}

__global__ void k_scan(){
  __shared__ int sA[2048], sB[2048];
  int b = blockIdx.x, tid = threadIdx.x;   // 1024
  for (int i = tid; i < 2048; i += 1024) sA[i] = (i < S_) ? g_indeg[b*S_+i] : 0;
  __syncthreads();
  int *src = sA, *dst = sB;
  for (int d = 1; d < 2048; d <<= 1){
    for (int i = tid; i < 2048; i += 1024) dst[i] = src[i] + (i >= d ? src[i-d] : 0);
    __syncthreads();
    int* t2 = src; src = dst; dst = t2;
  }
  if (tid == 0) g_off[b*(S_+1)] = 0;
  for (int i = tid; i < S_; i += 1024) g_off[b*(S_+1)+i+1] = src[i];
}

__global__ void k_fill(){
  int idx = blockIdx.x*256 + threadIdx.x;
  if (idx >= B_*E_) return;
  int b = idx / E_, e = idx - b*E_;
  int i = g_knn[idx];
  int slot = atomicAdd(&g_cursor[b*S_+i], 1);
  g_list[b*E_ + g_off[b*(S_+1)+i] + slot] = e;
}

// ---------------- weight packing ----------------
__global__ void k_pack_w2(const void* __restrict__ c0w2, const void* __restrict__ cw2,
                          const void* __restrict__ hw1){
  int gi = blockIdx.x*256 + threadIdx.x;
  if (gi >= 11*H_*H_) return;
  int mat = gi / (H_*H_), r = gi - mat*(H_*H_);
  int k = r / H_, n = r - (r/H_)*H_;
  float v;
  if (mat == 0)      v = LD(c0w2, (long)k*H_ + n);
  else if (mat <= 9) v = LD(cw2, (long)(mat-1)*H_*H_ + (long)k*H_ + n);
  else               v = LD(hw1, (long)k*H_ + n);
  int t = k>>5, q = (k>>3)&3, jj = k&7;
  g_w2p[(size_t)mat*H_*H_ + (((t*4+q)*H_ + n)*8 + jj)] = __float2bfloat16(v);
}

__global__ void k_pack_wc(const void* __restrict__ cw1){
  int gi = blockIdx.x*256 + threadIdx.x;
  if (gi >= 9*H_*384) return;
  int l = gi / (H_*384), r = gi - l*(H_*384);
  int k = r / 384, n = r - (r/384)*384;
  long base = (long)l*388*H_;
  float v;
  if (n < H_) v = LD(cw1, base + (long)k*H_ + n) - LD(cw1, base + (long)(H_+k)*H_ + n);
  else        v = LD(cw1, base + (long)(H_+k)*H_ + (n-H_));
  int t = k>>5, q = (k>>3)&3, jj = k&7;
  g_wcp[(size_t)l*(H_*384) + (((t*4+q)*384 + n)*8 + jj)] = __float2bfloat16(v);
}

__global__ void k_initout(const void* __restrict__ ub, const void* __restrict__ air, float* __restrict__ out){
  int gi = blockIdx.x*256 + threadIdx.x;   // 49152
  int n = (gi/3) % NN_;
  int b = gi / (K_*NN_*C_);
  float a = 1.f - LD(air, b*NN_+n);
  out[gi] = LD(ub, gi) * a;
}

// ---------------- conv0 node projection (K=10), weights in LDS ----------------
__global__ __launch_bounds__(256) void k_proj0(const void* __restrict__ w1){
  __shared__ float xs[16][10];
  __shared__ float wP[10][192];
  __shared__ float wQ[10][192];
  int tid = threadIdx.x;
  long rowBase = (long)blockIdx.x * 16;
  for (int idx = tid; idx < 1920; idx += 256){
    int f = idx / 192, n = idx - (idx/192)*192;
    float a = LD(w1, f*H_+n), b = LD(w1, (10+f)*H_+n);
    wP[f][n] = a - b; wQ[f][n] = b;
  }
  for (int idx = tid; idx < 160; idx += 256){
    int r = idx / 10, f = idx - (idx/10)*10;
    long row = rowBase + r; if (row >= NROW) row = NROW-1;
    xs[r][f] = g_x0[row*10 + f];
  }
  __syncthreads();
  for (int o = tid; o < 16*384; o += 256){
    int r = o / 384, n = o - (o/384)*384;
    long row = rowBase + r;
    if (row >= NROW) continue;
    float acc = 0.f;
    if (n < 192){
      #pragma unroll
      for (int f = 0; f < 10; ++f) acc += xs[r][f]*wP[f][n];
      g_P[row*192 + n] = acc;
    } else {
      int nc = n - 192;
      #pragma unroll
      for (int f = 0; f < 10; ++f) acc += xs[r][f]*wQ[f][nc];
      g_Qbf[row*192 + nc] = __float2bfloat16(acc);
    }
  }
}

// ---------------- MFMA GEMM: PQ projection, N=384, 16-row tiles ----------------
__global__ __launch_bounds__(256) void k_gemmPQ(int bOff, int M){
  const bf* A  = g_hbf;
  const bf* Bp = g_wcp + bOff;
  int wave = threadIdx.x >> 6, lane = threadIdx.x & 63;
  int q = lane >> 4, l16 = lane & 15;
  long rowBase = (long)blockIdx.x * 16;
  f32x4 acc[6];
  #pragma unroll
  for (int ct = 0; ct < 6; ++ct) acc[ct] = (f32x4){0.f,0.f,0.f,0.f};
  #pragma unroll
  for (int t = 0; t < 6; ++t){
    int kof = t*32 + q*8;
    long r = rowBase + l16; if (r >= M) r = M-1;
    bf16x8 af = *reinterpret_cast<const bf16x8*>(A + r*192 + kof);
    #pragma unroll
    for (int ct = 0; ct < 6; ++ct){
      int n = wave*96 + ct*16 + l16;
      bf16x8 bfr = *reinterpret_cast<const bf16x8*>(Bp + (((t*4+q)*384 + n)*8));
      acc[ct] = __builtin_amdgcn_mfma_f32_16x16x32_bf16(af, bfr, acc[ct], 0,0,0);
    }
  }
  #pragma unroll
  for (int ct = 0; ct < 6; ++ct){
    int col = wave*96 + ct*16 + l16;
    #pragma unroll
    for (int r = 0; r < 4; ++r){
      long row = rowBase + q*4 + r;
      if (row < M){
        float v = acc[ct][r];
        if (col < 192) g_P[row*192 + col] = v;
        else           g_Qbf[row*192 + (col-192)] = __float2bfloat16(v);
      }
    }
  }
}

// ---------------- fused MFMA GEMM (m2) + deg*b2 + LayerNorm + residual, 16-row tiles ----------------
template<int RES>
__global__ __launch_bounds__(256) void k_gemmln(const void* __restrict__ biasB, long biasO,
                                                const void* __restrict__ gB, long gO,
                                                const void* __restrict__ beB, long beO,
                                                int bOff, int M){
  const bf* A  = g_abf;
  const bf* Bp = g_w2p + bOff;
  int wave = threadIdx.x >> 6, lane = threadIdx.x & 63;
  int q = lane >> 4, l16 = lane & 15;
  long rowBase = (long)blockIdx.x * 16;
  f32x4 acc[3];
  #pragma unroll
  for (int ct = 0; ct < 3; ++ct) acc[ct] = (f32x4){0.f,0.f,0.f,0.f};
  #pragma unroll
  for (int t = 0; t < 6; ++t){
    int kof = t*32 + q*8;
    long r = rowBase + l16; if (r >= M) r = M-1;
    bf16x8 af = *reinterpret_cast<const bf16x8*>(A + r*192 + kof);
    #pragma unroll
    for (int ct = 0; ct < 3; ++ct){
      int n = wave*48 + ct*16 + l16;
      bf16x8 bfr = *reinterpret_cast<const bf16x8*>(Bp + (((t*4+q)*192 + n)*8));
      acc[ct] = __builtin_amdgcn_mfma_f32_16x16x32_bf16(af, bfr, acc[ct], 0,0,0);
    }
  }
  __shared__ float tile[16][200];
  __shared__ float srow[16], rrow[16];
  #pragma unroll
  for (int ct = 0; ct < 3; ++ct){
    int col = wave*48 + ct*16 + l16;
    float bb = LD(biasB, biasO + col);
    #pragma unroll
    for (int r = 0; r < 4; ++r){
      int lr = q*4 + r;
      long row = rowBase + lr;
      long rowc = (row < M) ? row : (M-1);
      int bk = (int)(rowc / S_); int i = (int)(rowc - (long)bk*S_); int b = bk >> 1;
      float degf = (float)(g_off[b*(S_+1)+i+1] - g_off[b*(S_+1)+i]);
      tile[lr][col] = acc[ct][r] + degf*bb;
    }
  }
  __syncthreads();
  {
    int lr = threadIdx.x >> 4;     // 0..15
    int k16 = threadIdx.x & 15;
    float s = 0.f, qq = 0.f;
    for (int c = k16; c < 192; c += 16){ float x = tile[lr][c]; s += x; qq += x*x; }
    #pragma unroll
    for (int o = 1; o < 16; o <<= 1){ s += __shfl_xor(s,o,64); qq += __shfl_xor(qq,o,64); }
    if (k16 == 0){
      float mu = s*(1.f/H_);
      float var = qq*(1.f/H_) - mu*mu;
      srow[lr] = mu;
      rrow[lr] = rsqrtf(fmaxf(var, 0.f) + 1e-5f);
    }
  }
  __syncthreads();
  for (int o = threadIdx.x; o < 16*192; o += 256){
    int lr = o / 192, col = o - (o/192)*192;
    long row = rowBase + lr;
    if (row < M){
      float y = (tile[lr][col] - srow[lr])*rrow[lr]*LD(gB,gO+col) + LD(beB,beO+col);
      if (RES) y += g_h[row*192 + col];
      g_h[row*192 + col] = y;
      g_hbf[row*192 + col] = __float2bfloat16(y);
    }
  }
}

// ---------------- head: LN + GEMM + gelu -> g_t ----------------
__global__ __launch_bounds__(256) void k_gemmhead(const void* __restrict__ gB,
                                                  const void* __restrict__ beB,
                                                  const void* __restrict__ biasB,
                                                  int bOff, int M){
  const bf* Bp = g_w2p + bOff;
  int wave = threadIdx.x >> 6, lane = threadIdx.x & 63;
  int q = lane >> 4, l16 = lane & 15;
  long rowBase = (long)blockIdx.x * 32;
  __shared__ float tile[32][200];
  __shared__ bf hb_s[32][216];
  __shared__ float srow[32], rrow[32];
  for (int o = threadIdx.x; o < 32*192; o += 256){
    int lr = o / 192, col = o - (o/192)*192;
    long row = rowBase + lr;
    long rowc = (row < M) ? row : (M-1);
    tile[lr][col] = g_h[rowc*192 + col];
  }
  __syncthreads();
  {
    int lr = threadIdx.x >> 3;
    int k8 = threadIdx.x & 7;
    float s = 0.f, qq = 0.f;
    for (int c = k8; c < 192; c += 8){ float x = tile[lr][c]; s += x; qq += x*x; }
    #pragma unroll
    for (int o = 1; o < 8; o <<= 1){ s += __shfl_xor(s,o,64); qq += __shfl_xor(qq,o,64); }
    if (k8 == 0){
      float mu = s*(1.f/H_);
      float var = qq*(1.f/H_) - mu*mu;
      srow[lr] = mu;
      rrow[lr] = rsqrtf(fmaxf(var, 0.f) + 1e-5f);
    }
  }
  __syncthreads();
  for (int o = threadIdx.x; o < 32*192; o += 256){
    int lr = o / 192, col = o - (o/192)*192;
    hb_s[lr][col] = __float2bfloat16((tile[lr][col] - srow[lr])*rrow[lr]*LD(gB,col) + LD(beB,col));
  }
  __syncthreads();
  f32x4 acc[2][3];
  #pragma unroll
  for (int rt = 0; rt < 2; ++rt)
    #pragma unroll
    for (int ct = 0; ct < 3; ++ct) acc[rt][ct] = (f32x4){0.f,0.f,0.f,0.f};
  #pragma unroll
  for (int t = 0; t < 6; ++t){
    int kof = t*32 + q*8;
    bf16x8 af[2], bfr[3];
    #pragma unroll
    for (int rt = 0; rt < 2; ++rt)
      af[rt] = *reinterpret_cast<const bf16x8*>(&hb_s[rt*16 + l16][kof]);
    #pragma unroll
    for (int ct = 0; ct < 3; ++ct){
      int n = wave*48 + ct*16 + l16;
      bfr[ct] = *reinterpret_cast<const bf16x8*>(Bp + (((t*4+q)*192 + n)*8));
    }
    #pragma unroll
    for (int rt = 0; rt < 2; ++rt)
      #pragma unroll
      for (int ct = 0; ct < 3; ++ct)
        acc[rt][ct] = __builtin_amdgcn_mfma_f32_16x16x32_bf16(af[rt], bfr[ct], acc[rt][ct], 0,0,0);
  }
  #pragma unroll
  for (int rt = 0; rt < 2; ++rt){
    #pragma unroll
    for (int ct = 0; ct < 3; ++ct){
      int col = wave*48 + ct*16 + l16;
      float bb = LD(biasB, col);
      #pragma unroll
      for (int r = 0; r < 4; ++r){
        long row = rowBase + rt*16 + q*4 + r;
        if (row < M) g_t[row*192 + col] = __float2bfloat16(gelu_f(acc[rt][ct][r] + bb));
      }
    }
  }
}

// ---------------- fused edge-compute + CSR aggregate (unroll x4) ----------------
__global__ __launch_bounds__(192) void k_aggedge(const void* __restrict__ w1cB, long w1cO,
                                                 const void* __restrict__ b1B, long b1O){
  int row = blockIdx.x;   // NROW
  int col = threadIdx.x;  // 192
  int bk = row / S_, i = row - bk*S_, b = bk >> 1;
  int off = g_off[b*(S_+1)+i];
  int deg = g_off[b*(S_+1)+i+1] - off;
  float w0 = LD(w1cB, w1cO+col),       w1v = LD(w1cB, w1cO+H_+col);
  float w2v = LD(w1cB, w1cO+2*H_+col), w3v = LD(w1cB, w1cO+3*H_+col);
  float base = g_P[(size_t)row*H_ + col] + LD(b1B, b1O+col);
  const int* lst = g_list + b*E_ + off;
  const bf* Q = g_Qbf + (size_t)bk*S_*H_;
  const float* EA = g_ea + (size_t)b*E_*4;
  float acc = 0.f;
  int d = 0;
  for (; d + 4 <= deg; d += 4){
    int e0 = lst[d], e1 = lst[d+1], e2 = lst[d+2], e3 = lst[d+3];
    float4 a0 = *reinterpret_cast<const float4*>(EA + (size_t)e0*4);
    float4 a1 = *reinterpret_cast<const float4*>(EA + (size_t)e1*4);
    float4 a2 = *reinterpret_cast<const float4*>(EA + (size_t)e2*4);
    float4 a3 = *reinterpret_cast<const float4*>(EA + (size_t)e3*4);
    float q0 = bf2f(Q[(size_t)(e0>>4)*H_ + col]);
    float q1 = bf2f(Q[(size_t)(e1>>4)*H_ + col]);
    float q2 = bf2f(Q[(size_t)(e2>>4)*H_ + col]);
    float q3 = bf2f(Q[(size_t)(e3>>4)*H_ + col]);
    acc += gelu_f(base + q0 + a0.x*w0 + a0.y*w1v + a0.z*w2v + a0.w*w3v);
    acc += gelu_f(base + q1 + a1.x*w0 + a1.y*w1v + a1.z*w2v + a1.w*w3v);
    acc += gelu_f(base + q2 + a2.x*w0 + a2.y*w1v + a2.z*w2v + a2.w*w3v);
    acc += gelu_f(base + q3 + a3.x*w0 + a3.y*w1v + a3.z*w2v + a3.w*w3v);
  }
  for (; d < deg; ++d){
    int e = lst[d];
    float4 a = *reinterpret_cast<const float4*>(EA + (size_t)e*4);
    float qv = bf2f(Q[(size_t)(e>>4)*H_ + col]);
    acc += gelu_f(base + qv + a.x*w0 + a.y*w1v + a.z*w2v + a.w*w3v);
  }
  g_abf[(size_t)row*H_ + col] = __float2bfloat16(acc);
}

// ---------------- final output rows ----------------
__global__ void k_headout(const void* __restrict__ w2, const void* __restrict__ b2,
                          const void* __restrict__ ub, const void* __restrict__ air,
                          float* __restrict__ out){
  int row = blockIdx.x*4 + (threadIdx.x >> 6);
  int lane = threadIdx.x & 63;
  if (row >= NROW) return;
  float t0 = bf2f(g_t[(size_t)row*H_ + lane]);
  float t1 = bf2f(g_t[(size_t)row*H_ + lane + 64]);
  float t2 = bf2f(g_t[(size_t)row*H_ + lane + 128]);
  float d[3];
  #pragma unroll
  for (int c = 0; c < 3; ++c){
    float p = t0*LD(w2,lane*3+c) + t1*LD(w2,(lane+64)*3+c) + t2*LD(w2,(lane+128)*3+c);
    #pragma unroll
    for (int o = 32; o; o >>= 1) p += __shfl_xor(p,o,64);
    d[c] = p + LD(b2,c);
  }
  if (lane == 0){
    int bk = row / S_, s = row - bk*S_, b = bk >> 1;
    float msk = g_masksel[b*S_+s];
    int node = g_topidx[b*S_+s];
    float am = 1.f - LD(air, b*NN_+node);
    #pragma unroll
    for (int c = 0; c < 3; ++c){
      long oi = ((long)bk*NN_ + node)*3 + c;
      out[oi] = (LD(ub,oi) + d[c]*msk)*am;
    }
  }
}

extern "C" void kernel_launch(void* const* d_in, const int* in_sizes, int n_in,
                              void* d_out, int out_size, void* d_ws, size_t ws_size,
                              hipStream_t stream) {
  (void)in_sizes; (void)n_in; (void)d_ws; (void)ws_size; (void)out_size;
  const void* u_base = d_in[0];
  const void* pos    = d_in[1];
  const void* vel    = d_in[2];
  const void* air    = d_in[3];
  const void* c0w1   = d_in[4];
  const void* c0b1   = d_in[5];
  const void* c0w2   = d_in[6];
  const void* c0b2   = d_in[7];
  const void* c0g    = d_in[8];
  const void* c0be   = d_in[9];
  const void* cw1    = d_in[10];
  const void* cb1    = d_in[11];
  const void* cw2    = d_in[12];
  const void* cb2    = d_in[13];
  const void* cg     = d_in[14];
  const void* cbe    = d_in[15];
  const void* hg     = d_in[16];
  const void* hbe    = d_in[17];
  const void* hw1    = d_in[18];
  const void* hb1    = d_in[19];
  const void* hw2    = d_in[20];
  const void* hb2    = d_in[21];
  float* out = (float*)d_out;

  k_vz<<<13, 256, 0, stream>>>(u_base, pos, vel);
  k_var<<<dim3(16, B_), 256, 0, stream>>>(vel);
  k_rank<<<dim3(NN_/4, B_), 256, 0, stream>>>();
  k_gather<<<13, 256, 0, stream>>>(pos, u_base, vel, air);
  k_knn<<<dim3((S_+3)/4, B_), 256, 0, stream>>>();
  k_scan<<<B_, 1024, 0, stream>>>();
  k_fill<<<205, 256, 0, stream>>>();
  k_pack_w2<<<1584, 256, 0, stream>>>(c0w2, cw2, hw1);
  k_pack_wc<<<2592, 256, 0, stream>>>(cw1);
  k_initout<<<192, 256, 0, stream>>>(u_base, air, out);
  k_proj0<<<410, 256, 0, stream>>>(c0w1);

  const int GN16 = (NROW + 15) / 16;   // 410
  for (int l = 0; l < 10; ++l){
    if (l > 0) k_gemmPQ<<<GN16, 256, 0, stream>>>((l-1)*H_*384, NROW);

    long w1cO = (l == 0) ? 20L*H_ : ((long)(l-1)*388 + 384)*H_;
    const void* w1cB = (l == 0) ? c0w1 : cw1;
    long lOff = (l == 0) ? 0 : (long)(l-1)*H_;
    const void* b1B = (l == 0) ? c0b1 : cb1;
    k_aggedge<<<NROW, 192, 0, stream>>>(w1cB, w1cO, b1B, lOff);

    const void* b2B = (l == 0) ? c0b2 : cb2;
    const void* gB  = (l == 0) ? c0g  : cg;
    const void* beB = (l == 0) ? c0be : cbe;
    if (l > 0) k_gemmln<1><<<GN16, 256, 0, stream>>>(b2B, lOff, gB, lOff, beB, lOff, l*H_*H_, NROW);
    else       k_gemmln<0><<<GN16, 256, 0, stream>>>(b2B, lOff, gB, lOff, beB, lOff, l*H_*H_, NROW);
  }

  k_gemmhead<<<(NROW + 31)/32, 256, 0, stream>>>(hg, hbe, hb1, 10*H_*H_, NROW);
  k_headout<<<NROW/4, 256, 0, stream>>>(hw2, hb2, u_base, air, out);
}